// Round 4
// baseline (172.635 us; speedup 1.0000x reference)
//
#include <hip/hip_runtime.h>

// Head attention forward, MI355X gfx950.
// B=8, T=2048, C=1024, H=64. Scale C^-0.5*log2e folded into q at gemm epilogue.
// R10 = R9 with qkv_gemm rewritten as a BARRIER-FREE, LDS-FREE streaming GEMM:
// each wave owns one 16-row m-tile x 96 cols (6 n-tiles); A-fragments are
// loaded directly from global x (2 float4 + cvt per K=32 step -- the mfma
// A layout lane(l15,quad)=A[l15][quad*8..+7] makes this a coalesced load);
// B streams from L2-resident Wct. Register-only 1-step prefetch; no
// __syncthreads, no inline-asm waits, no sched_barrier -- compiler schedules.
// 2048 independent waves = 8 waves/CU. x read exactly once (HBM floor ~11us).
// flash/freduce/wpack unchanged from R7.
//
// ws layout (u16/bf16):
//   [0, BTH) k [b][t][h] | [BTH, 2BTH) q' | [2BTH, 3BTH) vt [b][h][t]
//   [3BTH, +192K) Wct [n][k]  n: 0..63=Wk, 64..127=Wq, 128..191=Wv
//   then f32 partials: slot = (b*128+qt)*8 + c, 1040 f32 each (~34 MB)

#define B_ 8
#define T_ 2048
#define C_ 1024
#define H_ 64
#define BTH (B_ * T_ * H_)

typedef unsigned short u16;
typedef float f32x4 __attribute__((ext_vector_type(4)));
typedef __bf16 bf16x8 __attribute__((ext_vector_type(8)));
#define AS1 __attribute__((address_space(1)))
#define AS3 __attribute__((address_space(3)))

__device__ __forceinline__ u16 f2bf(float f) {
  union { float f; unsigned u; } c; c.f = f;
  unsigned u = c.u;
  return (u16)((u + 0x7FFFu + ((u >> 16) & 1u)) >> 16);  // RNE
}

__device__ __forceinline__ bf16x8 cvt8(const float4 a, const float4 b) {
  bf16x8 r;
  r[0] = (__bf16)a.x; r[1] = (__bf16)a.y; r[2] = (__bf16)a.z; r[3] = (__bf16)a.w;
  r[4] = (__bf16)b.x; r[5] = (__bf16)b.y; r[6] = (__bf16)b.z; r[7] = (__bf16)b.w;
  return r;
}

// ---------------------------------------------------------------------------
// wpack: Wct[g*64+h][k] = W_g[k][h], bf16. grid (3,16), block 256.
// ---------------------------------------------------------------------------
__global__ __launch_bounds__(256)
void wpack(const float* __restrict__ Wk, const float* __restrict__ Wq,
           const float* __restrict__ Wv, u16* __restrict__ Wct) {
  const int g  = blockIdx.x;
  const int k0 = blockIdx.y * 64;
  const float* __restrict__ W = (g == 0) ? Wk : (g == 1) ? Wq : Wv;
#pragma unroll
  for (int it = 0; it < 16; ++it) {
    const int idx = it * 256 + threadIdx.x;
    const int kk = k0 + (idx >> 6), h = idx & 63;
    Wct[(size_t)(g * 64 + h) * C_ + kk] = f2bf(W[(size_t)kk * H_ + h]);
  }
}

// ---------------------------------------------------------------------------
// qkv_gemm: grid (512), block 256 (4 waves). NO LDS, NO BARRIERS.
// Wave w of block bid: col-half ch = bid&1 (96 cols), m-tile
// mt = (bid>>1)*4 + w (16 rows). Per K=32 step: A directly from x
// (lane(l15,quad) loads x[(mt*16+l15)*C + k0 + quad*8 .. +8) = 2 float4,
// cvt to bf16x8), B from Wct (6 x bf16x8). 6 MFMA/step, 32 steps.
// Register double-buffer, depth 1; waves of a block share the B stream
// (same ch, similar pace) -> L1 reuse. x read exactly once globally.
// ---------------------------------------------------------------------------
__global__ __launch_bounds__(256)
void qkv_gemm(const float* __restrict__ x, const u16* __restrict__ Wct,
              u16* __restrict__ ws) {
  const int tid  = threadIdx.x;
  const int wv   = tid >> 6, lane = tid & 63;
  const int l15 = lane & 15, quad = lane >> 4;
  const int ch = blockIdx.x & 1;                 // col half: cols ch*96..+95
  const int mt = (blockIdx.x >> 1) * 4 + wv;     // m-tile: rows mt*16..+15
  const int r0 = mt * 16;
  const float* __restrict__ xw = x + (size_t)(r0 + l15) * C_ + quad * 8;
  const u16*   __restrict__ bw = Wct + (size_t)(ch * 96 + l15) * C_ + quad * 8;
  const f32x4 z = {0.f, 0.f, 0.f, 0.f};
  f32x4 acc[6];
#pragma unroll
  for (int ni = 0; ni < 6; ++ni) acc[ni] = z;

  // prologue: load step 0
  float4 xa0 = *(const float4*)(xw);
  float4 xa1 = *(const float4*)(xw + 4);
  bf16x8 bfc[6];
#pragma unroll
  for (int ni = 0; ni < 6; ++ni)
    bfc[ni] = *(const bf16x8*)(bw + (size_t)ni * 16 * C_);

#pragma unroll 2
  for (int ks = 0; ks < 32; ++ks) {
    const int k1 = (ks + 1) * 32;
    float4 na0, na1;
    bf16x8 bfn[6];
    if (ks < 31) {  // prefetch next K-step (registers only)
      na0 = *(const float4*)(xw + k1);
      na1 = *(const float4*)(xw + k1 + 4);
#pragma unroll
      for (int ni = 0; ni < 6; ++ni)
        bfn[ni] = *(const bf16x8*)(bw + (size_t)ni * 16 * C_ + k1);
    }
    const bf16x8 af = cvt8(xa0, xa1);
#pragma unroll
    for (int ni = 0; ni < 6; ++ni)
      acc[ni] = __builtin_amdgcn_mfma_f32_16x16x32_bf16(af, bfc[ni], acc[ni], 0, 0, 0);
    if (ks < 31) {
      xa0 = na0; xa1 = na1;
#pragma unroll
      for (int ni = 0; ni < 6; ++ni) bfc[ni] = bfn[ni];
    }
  }

  // epilogue: col = ch*96 + ni*16 + l15; row = r0 + quad*4 + r
  const float SCLL = 0.03125f * 1.44269504088896f;  // C^-0.5 * log2(e) -> q
  const int bb = r0 >> 11;
  const int tb = (r0 & 2047) + quad * 4;
#pragma unroll
  for (int ni = 0; ni < 6; ++ni) {
    const int col = ch * 96 + ni * 16 + l15;
    const int g = col >> 6, h = col & 63;
    f32x4 a = acc[ni];
    if (g == 1) { a[0] *= SCLL; a[1] *= SCLL; a[2] *= SCLL; a[3] *= SCLL; }
    if (g < 2) {
      u16* op = ws + (size_t)g * BTH + (size_t)(r0 + quad * 4) * H_ + h;
#pragma unroll
      for (int r = 0; r < 4; ++r) op[(size_t)r * H_] = f2bf(a[r]);
    } else {
      uint2 pk;
      pk.x = (unsigned)f2bf(a[0]) | ((unsigned)f2bf(a[1]) << 16);
      pk.y = (unsigned)f2bf(a[2]) | ((unsigned)f2bf(a[3]) << 16);
      *(uint2*)(ws + (size_t)2 * BTH + (size_t)(bb * H_ + h) * T_ + tb) = pk;
    }
  }
}

// ---------------------------------------------------------------------------
// flash: grid (144, 8), block 256 (4 waves). Work item = (b, u, c):
//   q-tiles qt = 4u+wv (wv=0..3) all have nst = u+1 64-key steps; chunk c
//   covers steps [4c, min(4c+4, u+1)). Chunk table over bx in [0,144):
//   off(c) = 34c - 2c^2, u = 4c + (bx - off(c)); bx reversed so the
//   all-4-step deep chunks dispatch first.
// (unchanged from R7)
// ---------------------------------------------------------------------------
__global__ __launch_bounds__(256)
void flash(const u16* __restrict__ ws, float* __restrict__ fpart) {
  __shared__ u16 Ks[2][64 * 64];   // 8 KB each
  __shared__ u16 Vs[2][64 * 64];
  __shared__ __bf16 Pt[4][16 * 72];
  const u16* __restrict__ kg = ws;
  const u16* __restrict__ qg = ws + BTH;
  const u16* __restrict__ vt = ws + (size_t)2 * BTH;
  const int b  = blockIdx.y;
  const int bx = 143 - (int)blockIdx.x;  // deep (all-4-step) chunks first
  int c = 0;
#pragma unroll
  for (int t = 1; t < 8; ++t)
    if (34 * t - 2 * t * t <= bx) c = t;
  const int u = 4 * c + (bx - (34 * c - 2 * c * c));
  const int tid  = threadIdx.x;
  const int wv   = tid >> 6;
  const int lane = tid & 63;
  const int l15  = lane & 15, quad = lane >> 4;
  const int qt   = 4 * u + wv;
  const int t0   = qt * 16;
  const int st0  = 4 * c;
  const int stE  = (st0 + 4 < u + 1) ? st0 + 4 : u + 1;
  const u16* kb0 = kg + (size_t)b * T_ * H_;
  const u16* vb0 = vt + (size_t)b * H_ * T_;
  // staging geometry: slot = jj*256 + tid; row = slot>>3 = jj*32+(tid>>3)
  const int srow = tid >> 3, scp = tid & 7;
  // q fragments (pre-scaled by C^-0.5*log2e in gemm)
  const u16* qrow = qg + ((size_t)(b * T_ + t0 + l15)) * H_ + quad * 8;
  const bf16x8 qf0 = *(const bf16x8*)qrow;
  const bf16x8 qf1 = *(const bf16x8*)(qrow + 32);
  __bf16* pt = &Pt[wv][0];
  const f32x4 z = {0.f, 0.f, 0.f, 0.f};
  f32x4 o[4];
  float lr[4] = {0.f, 0.f, 0.f, 0.f};
#pragma unroll
  for (int hi = 0; hi < 4; ++hi) o[hi] = z;

  // prologue: stage step st0 into buf 0
  {
    const int s00 = st0 * 64;
#pragma unroll
    for (int jj = 0; jj < 2; ++jj) {
      const int row = jj * 32 + srow;
      const int sc  = scp ^ (row & 7);
      __builtin_amdgcn_global_load_lds(
          (const AS1 unsigned*)(kb0 + (size_t)(s00 + row) * H_ + sc * 8),
          (AS3 unsigned*)(&Ks[0][(jj * 256 + tid) * 8]), 16, 0, 0);
      __builtin_amdgcn_global_load_lds(
          (const AS1 unsigned*)(vb0 + (size_t)row * T_ + s00 + sc * 8),
          (AS3 unsigned*)(&Vs[0][(jj * 256 + tid) * 8]), 16, 0, 0);
    }
  }
  __syncthreads();

#pragma unroll 1
  for (int st = st0; st < stE; ++st) {
    const int cur = (st - st0) & 1;
    if (st + 1 < stE) {  // stage next into other buffer
      const int s1 = (st + 1) * 64;
#pragma unroll
      for (int jj = 0; jj < 2; ++jj) {
        const int row = jj * 32 + srow;
        const int sc  = scp ^ (row & 7);
        __builtin_amdgcn_global_load_lds(
            (const AS1 unsigned*)(kb0 + (size_t)(s1 + row) * H_ + sc * 8),
            (AS3 unsigned*)(&Ks[cur ^ 1][(jj * 256 + tid) * 8]), 16, 0, 0);
        __builtin_amdgcn_global_load_lds(
            (const AS1 unsigned*)(vb0 + (size_t)row * T_ + s1 + sc * 8),
            (AS3 unsigned*)(&Vs[cur ^ 1][(jj * 256 + tid) * 8]), 16, 0, 0);
      }
    }
    // ---- compute on buf cur ----
    const u16* Kc = &Ks[cur][0];
    const u16* Vc = &Vs[cur][0];
    const int sw = (l15 & 7);
    f32x4 s[4];
#pragma unroll
    for (int ni = 0; ni < 4; ++ni) {
      const u16* kr = Kc + (ni * 16 + l15) * 64;
      const bf16x8 k0 = *(const bf16x8*)(kr + ((quad       ^ sw) * 8));
      const bf16x8 k1 = *(const bf16x8*)(kr + (((4 + quad) ^ sw) * 8));
      s[ni] = __builtin_amdgcn_mfma_f32_16x16x32_bf16(qf0, k0, z, 0, 0, 0);
      s[ni] = __builtin_amdgcn_mfma_f32_16x16x32_bf16(qf1, k1, s[ni], 0, 0, 0);
    }
    if (st == u) {  // causal mask (only the tile's final step crosses diagonal)
      const int s0 = st * 64;
#pragma unroll
      for (int ni = 0; ni < 4; ++ni)
#pragma unroll
        for (int r = 0; r < 4; ++r)
          if (s0 + ni * 16 + l15 > t0 + quad * 4 + r) s[ni][r] = -1e30f;
    }
    float p[4][4];
#pragma unroll
    for (int ni = 0; ni < 4; ++ni)
#pragma unroll
      for (int r = 0; r < 4; ++r) p[ni][r] = __builtin_amdgcn_exp2f(s[ni][r]);
#pragma unroll
    for (int r = 0; r < 4; ++r)
      lr[r] += (p[0][r] + p[1][r]) + (p[2][r] + p[3][r]);
    // P: C-layout -> A-layout via per-wave LDS (wave-local fence only)
#pragma unroll
    for (int ni = 0; ni < 4; ++ni)
#pragma unroll
      for (int r = 0; r < 4; ++r)
        pt[(quad * 4 + r) * 72 + ni * 16 + l15] = (__bf16)p[ni][r];
    asm volatile("s_waitcnt lgkmcnt(0)" ::: "memory");
    const bf16x8 pa0 = *(const bf16x8*)(pt + l15 * 72 + quad * 8);
    const bf16x8 pa1 = *(const bf16x8*)(pt + l15 * 72 + 32 + quad * 8);
    asm volatile("" ::: "memory");
#pragma unroll
    for (int hi = 0; hi < 4; ++hi) {
      const u16* vr = Vc + (hi * 16 + l15) * 64;
      const bf16x8 v0 = *(const bf16x8*)(vr + ((quad       ^ sw) * 8));
      const bf16x8 v1 = *(const bf16x8*)(vr + (((4 + quad) ^ sw) * 8));
      o[hi] = __builtin_amdgcn_mfma_f32_16x16x32_bf16(pa0, v0, o[hi], 0, 0, 0);
      o[hi] = __builtin_amdgcn_mfma_f32_16x16x32_bf16(pa1, v1, o[hi], 0, 0, 0);
    }
    __syncthreads();  // everyone done with cur; next-glds drained
  }
  // epilogue: row-sum lr across the 16 lanes of each quad, write f32 partial
#pragma unroll
  for (int d = 1; d < 16; d <<= 1)
#pragma unroll
    for (int r = 0; r < 4; ++r) lr[r] += __shfl_xor(lr[r], d, 64);
  float* po = fpart + (size_t)((b * 128 + qt) * 8 + c) * 1040;
#pragma unroll
  for (int hi = 0; hi < 4; ++hi)
#pragma unroll
    for (int r = 0; r < 4; ++r)
      po[(quad * 4 + r) * 64 + hi * 16 + l15] = o[hi][r];
  if (l15 == 0) {
#pragma unroll
    for (int r = 0; r < 4; ++r) po[1024 + quad * 4 + r] = lr[r];
  }
}

// ---------------------------------------------------------------------------
// freduce: grid (128, 8), block 256. Block (qt, b): sum nc = (qt>>4)+1 chunk
// partials (deterministic order) and normalize by l. Thread t owns float4 at
// element 4t: row = t>>4, cols (4t)&63.  (unchanged from R7)
// ---------------------------------------------------------------------------
__global__ __launch_bounds__(256)
void freduce(const float* __restrict__ fpart, float* __restrict__ out) {
  const int qt  = blockIdx.x;
  const int b   = blockIdx.y;
  const int tid = threadIdx.x;
  const int nc  = (qt >> 4) + 1;  // ceil(((qt>>2)+1)/4)
  const float* __restrict__ pb = fpart + (size_t)(b * 128 + qt) * 8 * 1040;
  __shared__ float ls[16];
  if (tid < 16) {
    float s = 0.f;
#pragma unroll 1
    for (int i = 0; i < nc; ++i) s += pb[(size_t)i * 1040 + 1024 + tid];
    ls[tid] = s;
  }
  __syncthreads();
  f32x4 a = {0.f, 0.f, 0.f, 0.f};
#pragma unroll 1
  for (int i = 0; i < nc; ++i)
    a += *(const f32x4*)(pb + (size_t)i * 1040 + tid * 4);
  const float inv = 1.0f / ls[tid >> 4];
  a[0] *= inv; a[1] *= inv; a[2] *= inv; a[3] *= inv;
  *(f32x4*)(out + (size_t)(b * T_ + qt * 16 + (tid >> 4)) * H_ + ((tid * 4) & 63)) = a;
}

extern "C" void kernel_launch(void* const* d_in, const int* in_sizes, int n_in,
                              void* d_out, int out_size, void* d_ws, size_t ws_size,
                              hipStream_t stream) {
  const float* x  = (const float*)d_in[0];
  const float* Wk = (const float*)d_in[1];
  const float* Wq = (const float*)d_in[2];
  const float* Wv = (const float*)d_in[3];
  u16*   ws  = (u16*)d_ws;
  u16*   Wct = ws + (size_t)3 * BTH;
  float* fpart = (float*)(ws + (size_t)3 * BTH + 192 * 1024);  // 16B-aligned
  float* out = (float*)d_out;
  wpack<<<dim3(3, 16), 256, 0, stream>>>(Wk, Wq, Wv, Wct);
  qkv_gemm<<<dim3(512), 256, 0, stream>>>(x, Wct, ws);
  flash<<<dim3(144, B_), 256, 0, stream>>>(ws, fpart);
  freduce<<<dim3(128, B_), 256, 0, stream>>>(fpart, out);
}

// Round 6
// 160.147 us; speedup vs baseline: 1.0780x; 1.0780x over previous
//
#include <hip/hip_runtime.h>

// Head attention forward, MI355X gfx950.
// B=8, T=2048, C=1024, H=64. Scale C^-0.5*log2e folded into q at gemm epilogue.
// R12 = R11 resubmitted verbatim (R5 bench failed on container acquisition,
// not kernel): qkv_gemm = proven naive 2-barrier LDS structure (R6 style)
// with doubled occupancy: 16-row x 192-col tiles, grid 1024, block 256
// (4 waves), 4 blocks/CU = 16 waves/CU (__launch_bounds__(256,4)).
// No inline asm, no sched_barrier: compiler schedules. x loads issued before
// B loads. x read exactly once. flash/freduce/wpack unchanged from R7.
//
// ws layout (u16/bf16):
//   [0, BTH) k [b][t][h] | [BTH, 2BTH) q' | [2BTH, 3BTH) vt [b][h][t]
//   [3BTH, +192K) Wct [n][k]  n: 0..63=Wk, 64..127=Wq, 128..191=Wv
//   then f32 partials: slot = (b*128+qt)*8 + c, 1040 f32 each (~34 MB)

#define B_ 8
#define T_ 2048
#define C_ 1024
#define H_ 64
#define BTH (B_ * T_ * H_)

typedef unsigned short u16;
typedef float f32x4 __attribute__((ext_vector_type(4)));
typedef __bf16 bf16x8 __attribute__((ext_vector_type(8)));
#define AS1 __attribute__((address_space(1)))
#define AS3 __attribute__((address_space(3)))

__device__ __forceinline__ u16 f2bf(float f) {
  union { float f; unsigned u; } c; c.f = f;
  unsigned u = c.u;
  return (u16)((u + 0x7FFFu + ((u >> 16) & 1u)) >> 16);  // RNE
}

__device__ __forceinline__ bf16x8 cvt8(const float4 a, const float4 b) {
  bf16x8 r;
  r[0] = (__bf16)a.x; r[1] = (__bf16)a.y; r[2] = (__bf16)a.z; r[3] = (__bf16)a.w;
  r[4] = (__bf16)b.x; r[5] = (__bf16)b.y; r[6] = (__bf16)b.z; r[7] = (__bf16)b.w;
  return r;
}

// ---------------------------------------------------------------------------
// wpack: Wct[g*64+h][k] = W_g[k][h], bf16. grid (3,16), block 256.
// ---------------------------------------------------------------------------
__global__ __launch_bounds__(256)
void wpack(const float* __restrict__ Wk, const float* __restrict__ Wq,
           const float* __restrict__ Wv, u16* __restrict__ Wct) {
  const int g  = blockIdx.x;
  const int k0 = blockIdx.y * 64;
  const float* __restrict__ W = (g == 0) ? Wk : (g == 1) ? Wq : Wv;
#pragma unroll
  for (int it = 0; it < 16; ++it) {
    const int idx = it * 256 + threadIdx.x;
    const int kk = k0 + (idx >> 6), h = idx & 63;
    Wct[(size_t)(g * 64 + h) * C_ + kk] = f2bf(W[(size_t)kk * H_ + h]);
  }
}

// ---------------------------------------------------------------------------
// qkv_gemm: grid (1024), block 256 (4 waves). Tile 16 rows x 192 cols, BK=128.
// Wave w: cols 48w..48w+47 (3 n-tiles) x the single 16-row m-tile.
// 4 blocks/CU (8 KB LDS, <=128 VGPR) = 16 waves/CU.
// LDS A: bf16 [2 buf][16 rows][16 chunks of 8], chunk c at c' = c ^ (row&15).
//   stage: thread t: row=t>>4, seg=t&15 -> 8 f32 (2 float4), one bf16x8 write
//          at chunk seg^(row&15).
//   read:  frag(f): row=l15, chunk (4f+quad)^l15.
// Step (R6-proven naive order): [load x 2xfloat4][load B 12xbf16x8]
//   [syncthreads][cvt+ds_write][syncthreads][4x ds_read_b128 + 12 MFMA].
// ---------------------------------------------------------------------------
__global__ __launch_bounds__(256, 4)
void qkv_gemm(const float* __restrict__ x, const u16* __restrict__ Wct,
              u16* __restrict__ ws) {
  __shared__ u16 As[2][16 * 128];  // 8 KB
  const int tid  = threadIdx.x;
  const int wave = tid >> 6, lane = tid & 63;
  const int l15 = lane & 15, quad = lane >> 4;
  const int r0 = blockIdx.x * 16;
  // staging: 16 threads/row, each 8 f32 = 1 chunk of 8
  const int srow = tid >> 4, sseg = tid & 15;
  const float* __restrict__ xsrc = x + (size_t)(r0 + srow) * C_ + sseg * 8;
  const int sc = (sseg ^ (srow & 15)) * 8;
  u16* const wd0 = &As[0][srow * 128 + sc];
  u16* const wd1 = &As[1][srow * 128 + sc];
  // compute-side bases
  const u16* __restrict__ wp = Wct + (size_t)(wave * 48 + l15) * C_ + quad * 8;
  const u16* const ard = As[0] + l15 * 128;  // + cur*2048 selects buffer
  const f32x4 z = {0.f, 0.f, 0.f, 0.f};
  f32x4 acc[3];
#pragma unroll
  for (int ni = 0; ni < 3; ++ni) acc[ni] = z;

#pragma unroll 1
  for (int ks = 0; ks < 8; ++ks) {
    const int k0 = ks * 128;
    const int cur = ks & 1;
    // x loads first (consumed at ds_write), B loads after (consumed post-bar;
    // stay in flight through the cvt's vmcnt wait)
    float4 xa0 = *(const float4*)(xsrc + k0);
    float4 xa1 = *(const float4*)(xsrc + k0 + 4);
    bf16x8 Bf[3][4];
#pragma unroll
    for (int ni = 0; ni < 3; ++ni)
#pragma unroll
      for (int f = 0; f < 4; ++f)
        Bf[ni][f] = *(const bf16x8*)(wp + (size_t)ni * 16 * C_ + k0 + f * 32);
    __syncthreads();  // all waves done reading previous buffer's counterpart
    *(bf16x8*)(cur ? wd1 : wd0) = cvt8(xa0, xa1);
    __syncthreads();  // staged data visible
    const u16* ac = ard + cur * (16 * 128);
#pragma unroll
    for (int f = 0; f < 4; ++f) {
      const int co = ((4 * f + quad) ^ l15) * 8;
      const bf16x8 a = *(const bf16x8*)(ac + co);
#pragma unroll
      for (int ni = 0; ni < 3; ++ni)
        acc[ni] = __builtin_amdgcn_mfma_f32_16x16x32_bf16(a, Bf[ni][f], acc[ni], 0, 0, 0);
    }
  }
  // epilogue: col = wave*48 + ni*16 + l15 (g=col>>6 wave-uniform per ni)
  const float SCLL = 0.03125f * 1.44269504088896f;  // C^-0.5 * log2(e) -> q
  const int bb = r0 >> 11;
  const int tb = (r0 & 2047) + quad * 4;
#pragma unroll
  for (int ni = 0; ni < 3; ++ni) {
    const int col = wave * 48 + ni * 16 + l15;
    const int g = col >> 6, h = col & 63;
    f32x4 a = acc[ni];
    if (g == 1) { a[0] *= SCLL; a[1] *= SCLL; a[2] *= SCLL; a[3] *= SCLL; }
    if (g < 2) {
      u16* op = ws + (size_t)g * BTH + (size_t)(r0 + quad * 4) * H_ + h;
#pragma unroll
      for (int r = 0; r < 4; ++r) op[(size_t)r * H_] = f2bf(a[r]);
    } else {
      uint2 pk;
      pk.x = (unsigned)f2bf(a[0]) | ((unsigned)f2bf(a[1]) << 16);
      pk.y = (unsigned)f2bf(a[2]) | ((unsigned)f2bf(a[3]) << 16);
      *(uint2*)(ws + (size_t)2 * BTH + (size_t)(bb * H_ + h) * T_ + tb) = pk;
    }
  }
}

// ---------------------------------------------------------------------------
// flash: grid (144, 8), block 256 (4 waves). Work item = (b, u, c):
//   q-tiles qt = 4u+wv (wv=0..3) all have nst = u+1 64-key steps; chunk c
//   covers steps [4c, min(4c+4, u+1)). Chunk table over bx in [0,144):
//   off(c) = 34c - 2c^2, u = 4c + (bx - off(c)); bx reversed so the
//   all-4-step deep chunks dispatch first.
// (unchanged from R7)
// ---------------------------------------------------------------------------
__global__ __launch_bounds__(256)
void flash(const u16* __restrict__ ws, float* __restrict__ fpart) {
  __shared__ u16 Ks[2][64 * 64];   // 8 KB each
  __shared__ u16 Vs[2][64 * 64];
  __shared__ __bf16 Pt[4][16 * 72];
  const u16* __restrict__ kg = ws;
  const u16* __restrict__ qg = ws + BTH;
  const u16* __restrict__ vt = ws + (size_t)2 * BTH;
  const int b  = blockIdx.y;
  const int bx = 143 - (int)blockIdx.x;  // deep (all-4-step) chunks first
  int c = 0;
#pragma unroll
  for (int t = 1; t < 8; ++t)
    if (34 * t - 2 * t * t <= bx) c = t;
  const int u = 4 * c + (bx - (34 * c - 2 * c * c));
  const int tid  = threadIdx.x;
  const int wv   = tid >> 6;
  const int lane = tid & 63;
  const int l15  = lane & 15, quad = lane >> 4;
  const int qt   = 4 * u + wv;
  const int t0   = qt * 16;
  const int st0  = 4 * c;
  const int stE  = (st0 + 4 < u + 1) ? st0 + 4 : u + 1;
  const u16* kb0 = kg + (size_t)b * T_ * H_;
  const u16* vb0 = vt + (size_t)b * H_ * T_;
  // staging geometry: slot = jj*256 + tid; row = slot>>3 = jj*32+(tid>>3)
  const int srow = tid >> 3, scp = tid & 7;
  // q fragments (pre-scaled by C^-0.5*log2e in gemm)
  const u16* qrow = qg + ((size_t)(b * T_ + t0 + l15)) * H_ + quad * 8;
  const bf16x8 qf0 = *(const bf16x8*)qrow;
  const bf16x8 qf1 = *(const bf16x8*)(qrow + 32);
  __bf16* pt = &Pt[wv][0];
  const f32x4 z = {0.f, 0.f, 0.f, 0.f};
  f32x4 o[4];
  float lr[4] = {0.f, 0.f, 0.f, 0.f};
#pragma unroll
  for (int hi = 0; hi < 4; ++hi) o[hi] = z;

  // prologue: stage step st0 into buf 0
  {
    const int s00 = st0 * 64;
#pragma unroll
    for (int jj = 0; jj < 2; ++jj) {
      const int row = jj * 32 + srow;
      const int sc  = scp ^ (row & 7);
      __builtin_amdgcn_global_load_lds(
          (const AS1 unsigned*)(kb0 + (size_t)(s00 + row) * H_ + sc * 8),
          (AS3 unsigned*)(&Ks[0][(jj * 256 + tid) * 8]), 16, 0, 0);
      __builtin_amdgcn_global_load_lds(
          (const AS1 unsigned*)(vb0 + (size_t)row * T_ + s00 + sc * 8),
          (AS3 unsigned*)(&Vs[0][(jj * 256 + tid) * 8]), 16, 0, 0);
    }
  }
  __syncthreads();

#pragma unroll 1
  for (int st = st0; st < stE; ++st) {
    const int cur = (st - st0) & 1;
    if (st + 1 < stE) {  // stage next into other buffer
      const int s1 = (st + 1) * 64;
#pragma unroll
      for (int jj = 0; jj < 2; ++jj) {
        const int row = jj * 32 + srow;
        const int sc  = scp ^ (row & 7);
        __builtin_amdgcn_global_load_lds(
            (const AS1 unsigned*)(kb0 + (size_t)(s1 + row) * H_ + sc * 8),
            (AS3 unsigned*)(&Ks[cur ^ 1][(jj * 256 + tid) * 8]), 16, 0, 0);
        __builtin_amdgcn_global_load_lds(
            (const AS1 unsigned*)(vb0 + (size_t)row * T_ + s1 + sc * 8),
            (AS3 unsigned*)(&Vs[cur ^ 1][(jj * 256 + tid) * 8]), 16, 0, 0);
      }
    }
    // ---- compute on buf cur ----
    const u16* Kc = &Ks[cur][0];
    const u16* Vc = &Vs[cur][0];
    const int sw = (l15 & 7);
    f32x4 s[4];
#pragma unroll
    for (int ni = 0; ni < 4; ++ni) {
      const u16* kr = Kc + (ni * 16 + l15) * 64;
      const bf16x8 k0 = *(const bf16x8*)(kr + ((quad       ^ sw) * 8));
      const bf16x8 k1 = *(const bf16x8*)(kr + (((4 + quad) ^ sw) * 8));
      s[ni] = __builtin_amdgcn_mfma_f32_16x16x32_bf16(qf0, k0, z, 0, 0, 0);
      s[ni] = __builtin_amdgcn_mfma_f32_16x16x32_bf16(qf1, k1, s[ni], 0, 0, 0);
    }
    if (st == u) {  // causal mask (only the tile's final step crosses diagonal)
      const int s0 = st * 64;
#pragma unroll
      for (int ni = 0; ni < 4; ++ni)
#pragma unroll
        for (int r = 0; r < 4; ++r)
          if (s0 + ni * 16 + l15 > t0 + quad * 4 + r) s[ni][r] = -1e30f;
    }
    float p[4][4];
#pragma unroll
    for (int ni = 0; ni < 4; ++ni)
#pragma unroll
      for (int r = 0; r < 4; ++r) p[ni][r] = __builtin_amdgcn_exp2f(s[ni][r]);
#pragma unroll
    for (int r = 0; r < 4; ++r)
      lr[r] += (p[0][r] + p[1][r]) + (p[2][r] + p[3][r]);
    // P: C-layout -> A-layout via per-wave LDS (wave-local fence only)
#pragma unroll
    for (int ni = 0; ni < 4; ++ni)
#pragma unroll
      for (int r = 0; r < 4; ++r)
        pt[(quad * 4 + r) * 72 + ni * 16 + l15] = (__bf16)p[ni][r];
    asm volatile("s_waitcnt lgkmcnt(0)" ::: "memory");
    const bf16x8 pa0 = *(const bf16x8*)(pt + l15 * 72 + quad * 8);
    const bf16x8 pa1 = *(const bf16x8*)(pt + l15 * 72 + 32 + quad * 8);
    asm volatile("" ::: "memory");
#pragma unroll
    for (int hi = 0; hi < 4; ++hi) {
      const u16* vr = Vc + (hi * 16 + l15) * 64;
      const bf16x8 v0 = *(const bf16x8*)(vr + ((quad       ^ sw) * 8));
      const bf16x8 v1 = *(const bf16x8*)(vr + (((4 + quad) ^ sw) * 8));
      o[hi] = __builtin_amdgcn_mfma_f32_16x16x32_bf16(pa0, v0, o[hi], 0, 0, 0);
      o[hi] = __builtin_amdgcn_mfma_f32_16x16x32_bf16(pa1, v1, o[hi], 0, 0, 0);
    }
    __syncthreads();  // everyone done with cur; next-glds drained
  }
  // epilogue: row-sum lr across the 16 lanes of each quad, write f32 partial
#pragma unroll
  for (int d = 1; d < 16; d <<= 1)
#pragma unroll
    for (int r = 0; r < 4; ++r) lr[r] += __shfl_xor(lr[r], d, 64);
  float* po = fpart + (size_t)((b * 128 + qt) * 8 + c) * 1040;
#pragma unroll
  for (int hi = 0; hi < 4; ++hi)
#pragma unroll
    for (int r = 0; r < 4; ++r)
      po[(quad * 4 + r) * 64 + hi * 16 + l15] = o[hi][r];
  if (l15 == 0) {
#pragma unroll
    for (int r = 0; r < 4; ++r) po[1024 + quad * 4 + r] = lr[r];
  }
}

// ---------------------------------------------------------------------------
// freduce: grid (128, 8), block 256. Block (qt, b): sum nc = (qt>>4)+1 chunk
// partials (deterministic order) and normalize by l. Thread t owns float4 at
// element 4t: row = t>>4, cols (4t)&63.  (unchanged from R7)
// ---------------------------------------------------------------------------
__global__ __launch_bounds__(256)
void freduce(const float* __restrict__ fpart, float* __restrict__ out) {
  const int qt  = blockIdx.x;
  const int b   = blockIdx.y;
  const int tid = threadIdx.x;
  const int nc  = (qt >> 4) + 1;  // ceil(((qt>>2)+1)/4)
  const float* __restrict__ pb = fpart + (size_t)(b * 128 + qt) * 8 * 1040;
  __shared__ float ls[16];
  if (tid < 16) {
    float s = 0.f;
#pragma unroll 1
    for (int i = 0; i < nc; ++i) s += pb[(size_t)i * 1040 + 1024 + tid];
    ls[tid] = s;
  }
  __syncthreads();
  f32x4 a = {0.f, 0.f, 0.f, 0.f};
#pragma unroll 1
  for (int i = 0; i < nc; ++i)
    a += *(const f32x4*)(pb + (size_t)i * 1040 + tid * 4);
  const float inv = 1.0f / ls[tid >> 4];
  a[0] *= inv; a[1] *= inv; a[2] *= inv; a[3] *= inv;
  *(f32x4*)(out + (size_t)(b * T_ + qt * 16 + (tid >> 4)) * H_ + ((tid * 4) & 63)) = a;
}

extern "C" void kernel_launch(void* const* d_in, const int* in_sizes, int n_in,
                              void* d_out, int out_size, void* d_ws, size_t ws_size,
                              hipStream_t stream) {
  const float* x  = (const float*)d_in[0];
  const float* Wk = (const float*)d_in[1];
  const float* Wq = (const float*)d_in[2];
  const float* Wv = (const float*)d_in[3];
  u16*   ws  = (u16*)d_ws;
  u16*   Wct = ws + (size_t)3 * BTH;
  float* fpart = (float*)(ws + (size_t)3 * BTH + 192 * 1024);  // 16B-aligned
  float* out = (float*)d_out;
  wpack<<<dim3(3, 16), 256, 0, stream>>>(Wk, Wq, Wv, Wct);
  qkv_gemm<<<dim3(1024), 256, 0, stream>>>(x, Wct, ws);
  flash<<<dim3(144, B_), 256, 0, stream>>>(ws, fpart);
  freduce<<<dim3(128, B_), 256, 0, stream>>>(fpart, out);
}

// Round 7
// 134.666 us; speedup vs baseline: 1.2820x; 1.1892x over previous
//
#include <hip/hip_runtime.h>

// Head attention forward, MI355X gfx950.
// B=8, T=2048, C=1024, H=64. Scale C^-0.5*log2e folded into q at gemm epilogue.
// R13: qkv_gemm rebuilt around BULK B residency: grid 256 (1 block/CU),
// 512 threads (8 waves), 64-row m-tile x 192 cols, BK=128. Per K-step, B-slice
// [192][128] staged via 6x global_load_lds (49 KB) and x-slice [64][128]
// staged via reg-load->cvt->ds_write, both double-buffered, ONE __syncthreads
// per step (its vmcnt(0) drain = glds completion) -- the exact schedule the
// flash kernel has proven. XOR swizzle chunk^(row&7) on stage+read sides.
// B L2 issue cost drops ~16x vs per-step scattered reg loads; x read once.
// flash/freduce/wpack unchanged from R7.
//
// ws layout (u16/bf16):
//   [0, BTH) k [b][t][h] | [BTH, 2BTH) q' | [2BTH, 3BTH) vt [b][h][t]
//   [3BTH, +192K) Wct [n][k]  n: 0..63=Wk, 64..127=Wq, 128..191=Wv
//   then f32 partials: slot = (b*128+qt)*8 + c, 1040 f32 each (~34 MB)

#define B_ 8
#define T_ 2048
#define C_ 1024
#define H_ 64
#define BTH (B_ * T_ * H_)

typedef unsigned short u16;
typedef float f32x4 __attribute__((ext_vector_type(4)));
typedef __bf16 bf16x8 __attribute__((ext_vector_type(8)));
#define AS1 __attribute__((address_space(1)))
#define AS3 __attribute__((address_space(3)))

__device__ __forceinline__ u16 f2bf(float f) {
  union { float f; unsigned u; } c; c.f = f;
  unsigned u = c.u;
  return (u16)((u + 0x7FFFu + ((u >> 16) & 1u)) >> 16);  // RNE
}

__device__ __forceinline__ bf16x8 cvt8(const float4 a, const float4 b) {
  bf16x8 r;
  r[0] = (__bf16)a.x; r[1] = (__bf16)a.y; r[2] = (__bf16)a.z; r[3] = (__bf16)a.w;
  r[4] = (__bf16)b.x; r[5] = (__bf16)b.y; r[6] = (__bf16)b.z; r[7] = (__bf16)b.w;
  return r;
}

// ---------------------------------------------------------------------------
// wpack: Wct[g*64+h][k] = W_g[k][h], bf16. grid (3,16), block 256.
// ---------------------------------------------------------------------------
__global__ __launch_bounds__(256)
void wpack(const float* __restrict__ Wk, const float* __restrict__ Wq,
           const float* __restrict__ Wv, u16* __restrict__ Wct) {
  const int g  = blockIdx.x;
  const int k0 = blockIdx.y * 64;
  const float* __restrict__ W = (g == 0) ? Wk : (g == 1) ? Wq : Wv;
#pragma unroll
  for (int it = 0; it < 16; ++it) {
    const int idx = it * 256 + threadIdx.x;
    const int kk = k0 + (idx >> 6), h = idx & 63;
    Wct[(size_t)(g * 64 + h) * C_ + kk] = f2bf(W[(size_t)kk * H_ + h]);
  }
}

// ---------------------------------------------------------------------------
// qkv_gemm: grid (256), block 512 (8 waves). Tile 64 rows x 192 cols, BK=128.
// Wave w: wr=w>>2 (2 row-halves of 32), wc=w&3 (4 col-groups of 48).
// LDS (128 KB): Bs[2][192][16 chunks of 8] (96 KB), Xs[2][64][16 chunks] (32KB)
//   swizzle: source chunk c of row r stored at slot c ^ (r&7).
// B stage: 6 glds iters/step: slot=it*512+tid, row=slot>>4, cp=slot&15,
//   src chunk = cp^(row&7); dest linear (16 B/lane). x stage: thread t:
//   row=t>>3, cp=t&7 -> src chunks cp,cp+8 (4 float4), write slots
//   cp^(row&7), +8. Read (A or B): row=base+l15, chunk (kk*4+quad)^(l15&7).
// Step: [issue x f32 loads (next)] [issue 6 glds B (next)]
//   [compute cur: 4 kk x (2 A + 3 B ds_read, 6 MFMA)] [cvt+ds_write x next]
//   [__syncthreads: drains vmcnt (glds done) + lgkm].  (flash-proven schedule)
// ---------------------------------------------------------------------------
__global__ __launch_bounds__(512, 1)
void qkv_gemm(const float* __restrict__ x, const u16* __restrict__ Wct,
              u16* __restrict__ ws) {
  __shared__ u16 Bs[2][192 * 128];  // 96 KB
  __shared__ u16 Xs[2][64 * 128];   // 32 KB
  const int tid  = threadIdx.x;
  const int wv   = tid >> 6, lane = tid & 63;
  const int l15 = lane & 15, quad = lane >> 4;
  const int wr = wv >> 2, wc = wv & 3;
  const int r0 = blockIdx.x * 64;
  // x staging geometry
  const int xrow = tid >> 3, xcp = tid & 7;
  const int xw0 = (xcp ^ (xrow & 7)) * 8;          // elem offset of write slot
  const float* __restrict__ xsrc = x + (size_t)(r0 + xrow) * C_;
  u16* const xd0 = &Xs[0][xrow * 128 + xw0];
  u16* const xd1 = &Xs[1][xrow * 128 + xw0];
  // compute-side bases
  const int arow = wr * 32 + l15;
  const int brow = wc * 48 + l15;
  const int cksw = (l15 & 7);
  const f32x4 z = {0.f, 0.f, 0.f, 0.f};
  f32x4 acc[2][3];
#pragma unroll
  for (int m = 0; m < 2; ++m)
#pragma unroll
    for (int ni = 0; ni < 3; ++ni) acc[m][ni] = z;

  // ---- prologue: stage step 0 into buffer 0 ----
  float4 xr[4];
  xr[0] = *(const float4*)(xsrc + xcp * 8);
  xr[1] = *(const float4*)(xsrc + xcp * 8 + 4);
  xr[2] = *(const float4*)(xsrc + (xcp + 8) * 8);
  xr[3] = *(const float4*)(xsrc + (xcp + 8) * 8 + 4);
#pragma unroll
  for (int it = 0; it < 6; ++it) {
    const int slot = it * 512 + tid;
    const int row = slot >> 4, cp = slot & 15;
    const int sc = cp ^ (row & 7);
    __builtin_amdgcn_global_load_lds(
        (const AS1 unsigned*)(Wct + (size_t)row * C_ + sc * 8),
        (AS3 unsigned*)(&Bs[0][slot * 8]), 16, 0, 0);
  }
  *(bf16x8*)xd0 = cvt8(xr[0], xr[1]);
  *(bf16x8*)(xd0 + 64) = cvt8(xr[2], xr[3]);
  __syncthreads();

#pragma unroll 1
  for (int st = 0; st < 8; ++st) {
    const int cur = st & 1;
    const int co0 = cur * (64 * 128);   // Xs flat offset
    const int cb0 = cur * (192 * 128);  // Bs flat offset
    if (st < 7) {  // issue next-step staging (x first, then B glds)
      const int k1 = (st + 1) * 128;
      xr[0] = *(const float4*)(xsrc + k1 + xcp * 8);
      xr[1] = *(const float4*)(xsrc + k1 + xcp * 8 + 4);
      xr[2] = *(const float4*)(xsrc + k1 + (xcp + 8) * 8);
      xr[3] = *(const float4*)(xsrc + k1 + (xcp + 8) * 8 + 4);
#pragma unroll
      for (int it = 0; it < 6; ++it) {
        const int slot = it * 512 + tid;
        const int row = slot >> 4, cp = slot & 15;
        const int sc = cp ^ (row & 7);
        __builtin_amdgcn_global_load_lds(
            (const AS1 unsigned*)(Wct + (size_t)row * C_ + k1 + sc * 8),
            (AS3 unsigned*)(&Bs[cur ^ 1][slot * 8]), 16, 0, 0);
      }
    }
    // ---- compute on buffer cur ----
    const u16* Xc = &Xs[0][0] + co0;
    const u16* Bc = &Bs[0][0] + cb0;
#pragma unroll
    for (int kk = 0; kk < 4; ++kk) {
      const int co = (((kk * 4 + quad) ^ cksw)) * 8;
      const bf16x8 a0 = *(const bf16x8*)(Xc + arow * 128 + co);
      const bf16x8 a1 = *(const bf16x8*)(Xc + (arow + 16) * 128 + co);
#pragma unroll
      for (int ni = 0; ni < 3; ++ni) {
        const bf16x8 b = *(const bf16x8*)(Bc + (brow + ni * 16) * 128 + co);
        acc[0][ni] = __builtin_amdgcn_mfma_f32_16x16x32_bf16(a0, b, acc[0][ni], 0, 0, 0);
        acc[1][ni] = __builtin_amdgcn_mfma_f32_16x16x32_bf16(a1, b, acc[1][ni], 0, 0, 0);
      }
    }
    if (st < 7) {  // write next x tile (its readers finished before last bar)
      u16* xd = cur ? xd0 : xd1;
      *(bf16x8*)xd = cvt8(xr[0], xr[1]);
      *(bf16x8*)(xd + 64) = cvt8(xr[2], xr[3]);
    }
    __syncthreads();  // drains vmcnt (B glds done) + lgkm; readers synced
  }

  // epilogue: col = wc*48 + ni*16 + l15; row = r0 + wr*32 + m*16 + quad*4 + r
  const float SCLL = 0.03125f * 1.44269504088896f;  // C^-0.5 * log2(e) -> q
#pragma unroll
  for (int m = 0; m < 2; ++m) {
    const int rowg = r0 + wr * 32 + m * 16;
    const int bb = rowg >> 11;
    const int tb = (rowg & 2047) + quad * 4;
#pragma unroll
    for (int ni = 0; ni < 3; ++ni) {
      const int col = wc * 48 + ni * 16 + l15;
      const int g = col >> 6, h = col & 63;
      f32x4 a = acc[m][ni];
      if (g == 1) { a[0] *= SCLL; a[1] *= SCLL; a[2] *= SCLL; a[3] *= SCLL; }
      if (g < 2) {
        u16* op = ws + (size_t)g * BTH + (size_t)(rowg + quad * 4) * H_ + h;
#pragma unroll
        for (int r = 0; r < 4; ++r) op[(size_t)r * H_] = f2bf(a[r]);
      } else {
        uint2 pk;
        pk.x = (unsigned)f2bf(a[0]) | ((unsigned)f2bf(a[1]) << 16);
        pk.y = (unsigned)f2bf(a[2]) | ((unsigned)f2bf(a[3]) << 16);
        *(uint2*)(ws + (size_t)2 * BTH + (size_t)(bb * H_ + h) * T_ + tb) = pk;
      }
    }
  }
}

// ---------------------------------------------------------------------------
// flash: grid (144, 8), block 256 (4 waves). Work item = (b, u, c):
//   q-tiles qt = 4u+wv (wv=0..3) all have nst = u+1 64-key steps; chunk c
//   covers steps [4c, min(4c+4, u+1)). Chunk table over bx in [0,144):
//   off(c) = 34c - 2c^2, u = 4c + (bx - off(c)); bx reversed so the
//   all-4-step deep chunks dispatch first.
// (unchanged from R7)
// ---------------------------------------------------------------------------
__global__ __launch_bounds__(256)
void flash(const u16* __restrict__ ws, float* __restrict__ fpart) {
  __shared__ u16 Ks[2][64 * 64];   // 8 KB each
  __shared__ u16 Vs[2][64 * 64];
  __shared__ __bf16 Pt[4][16 * 72];
  const u16* __restrict__ kg = ws;
  const u16* __restrict__ qg = ws + BTH;
  const u16* __restrict__ vt = ws + (size_t)2 * BTH;
  const int b  = blockIdx.y;
  const int bx = 143 - (int)blockIdx.x;  // deep (all-4-step) chunks first
  int c = 0;
#pragma unroll
  for (int t = 1; t < 8; ++t)
    if (34 * t - 2 * t * t <= bx) c = t;
  const int u = 4 * c + (bx - (34 * c - 2 * c * c));
  const int tid  = threadIdx.x;
  const int wv   = tid >> 6;
  const int lane = tid & 63;
  const int l15  = lane & 15, quad = lane >> 4;
  const int qt   = 4 * u + wv;
  const int t0   = qt * 16;
  const int st0  = 4 * c;
  const int stE  = (st0 + 4 < u + 1) ? st0 + 4 : u + 1;
  const u16* kb0 = kg + (size_t)b * T_ * H_;
  const u16* vb0 = vt + (size_t)b * H_ * T_;
  // staging geometry: slot = jj*256 + tid; row = slot>>3 = jj*32+(tid>>3)
  const int srow = tid >> 3, scp = tid & 7;
  // q fragments (pre-scaled by C^-0.5*log2e in gemm)
  const u16* qrow = qg + ((size_t)(b * T_ + t0 + l15)) * H_ + quad * 8;
  const bf16x8 qf0 = *(const bf16x8*)qrow;
  const bf16x8 qf1 = *(const bf16x8*)(qrow + 32);
  __bf16* pt = &Pt[wv][0];
  const f32x4 z = {0.f, 0.f, 0.f, 0.f};
  f32x4 o[4];
  float lr[4] = {0.f, 0.f, 0.f, 0.f};
#pragma unroll
  for (int hi = 0; hi < 4; ++hi) o[hi] = z;

  // prologue: stage step st0 into buf 0
  {
    const int s00 = st0 * 64;
#pragma unroll
    for (int jj = 0; jj < 2; ++jj) {
      const int row = jj * 32 + srow;
      const int sc  = scp ^ (row & 7);
      __builtin_amdgcn_global_load_lds(
          (const AS1 unsigned*)(kb0 + (size_t)(s00 + row) * H_ + sc * 8),
          (AS3 unsigned*)(&Ks[0][(jj * 256 + tid) * 8]), 16, 0, 0);
      __builtin_amdgcn_global_load_lds(
          (const AS1 unsigned*)(vb0 + (size_t)row * T_ + s00 + sc * 8),
          (AS3 unsigned*)(&Vs[0][(jj * 256 + tid) * 8]), 16, 0, 0);
    }
  }
  __syncthreads();

#pragma unroll 1
  for (int st = st0; st < stE; ++st) {
    const int cur = (st - st0) & 1;
    if (st + 1 < stE) {  // stage next into other buffer
      const int s1 = (st + 1) * 64;
#pragma unroll
      for (int jj = 0; jj < 2; ++jj) {
        const int row = jj * 32 + srow;
        const int sc  = scp ^ (row & 7);
        __builtin_amdgcn_global_load_lds(
            (const AS1 unsigned*)(kb0 + (size_t)(s1 + row) * H_ + sc * 8),
            (AS3 unsigned*)(&Ks[cur ^ 1][(jj * 256 + tid) * 8]), 16, 0, 0);
        __builtin_amdgcn_global_load_lds(
            (const AS1 unsigned*)(vb0 + (size_t)row * T_ + s1 + sc * 8),
            (AS3 unsigned*)(&Vs[cur ^ 1][(jj * 256 + tid) * 8]), 16, 0, 0);
      }
    }
    // ---- compute on buf cur ----
    const u16* Kc = &Ks[cur][0];
    const u16* Vc = &Vs[cur][0];
    const int sw = (l15 & 7);
    f32x4 s[4];
#pragma unroll
    for (int ni = 0; ni < 4; ++ni) {
      const u16* kr = Kc + (ni * 16 + l15) * 64;
      const bf16x8 k0 = *(const bf16x8*)(kr + ((quad       ^ sw) * 8));
      const bf16x8 k1 = *(const bf16x8*)(kr + (((4 + quad) ^ sw) * 8));
      s[ni] = __builtin_amdgcn_mfma_f32_16x16x32_bf16(qf0, k0, z, 0, 0, 0);
      s[ni] = __builtin_amdgcn_mfma_f32_16x16x32_bf16(qf1, k1, s[ni], 0, 0, 0);
    }
    if (st == u) {  // causal mask (only the tile's final step crosses diagonal)
      const int s0 = st * 64;
#pragma unroll
      for (int ni = 0; ni < 4; ++ni)
#pragma unroll
        for (int r = 0; r < 4; ++r)
          if (s0 + ni * 16 + l15 > t0 + quad * 4 + r) s[ni][r] = -1e30f;
    }
    float p[4][4];
#pragma unroll
    for (int ni = 0; ni < 4; ++ni)
#pragma unroll
      for (int r = 0; r < 4; ++r) p[ni][r] = __builtin_amdgcn_exp2f(s[ni][r]);
#pragma unroll
    for (int r = 0; r < 4; ++r)
      lr[r] += (p[0][r] + p[1][r]) + (p[2][r] + p[3][r]);
    // P: C-layout -> A-layout via per-wave LDS (wave-local fence only)
#pragma unroll
    for (int ni = 0; ni < 4; ++ni)
#pragma unroll
      for (int r = 0; r < 4; ++r)
        pt[(quad * 4 + r) * 72 + ni * 16 + l15] = (__bf16)p[ni][r];
    asm volatile("s_waitcnt lgkmcnt(0)" ::: "memory");
    const bf16x8 pa0 = *(const bf16x8*)(pt + l15 * 72 + quad * 8);
    const bf16x8 pa1 = *(const bf16x8*)(pt + l15 * 72 + 32 + quad * 8);
    asm volatile("" ::: "memory");
#pragma unroll
    for (int hi = 0; hi < 4; ++hi) {
      const u16* vr = Vc + (hi * 16 + l15) * 64;
      const bf16x8 v0 = *(const bf16x8*)(vr + ((quad       ^ sw) * 8));
      const bf16x8 v1 = *(const bf16x8*)(vr + (((4 + quad) ^ sw) * 8));
      o[hi] = __builtin_amdgcn_mfma_f32_16x16x32_bf16(pa0, v0, o[hi], 0, 0, 0);
      o[hi] = __builtin_amdgcn_mfma_f32_16x16x32_bf16(pa1, v1, o[hi], 0, 0, 0);
    }
    __syncthreads();  // everyone done with cur; next-glds drained
  }
  // epilogue: row-sum lr across the 16 lanes of each quad, write f32 partial
#pragma unroll
  for (int d = 1; d < 16; d <<= 1)
#pragma unroll
    for (int r = 0; r < 4; ++r) lr[r] += __shfl_xor(lr[r], d, 64);
  float* po = fpart + (size_t)((b * 128 + qt) * 8 + c) * 1040;
#pragma unroll
  for (int hi = 0; hi < 4; ++hi)
#pragma unroll
    for (int r = 0; r < 4; ++r)
      po[(quad * 4 + r) * 64 + hi * 16 + l15] = o[hi][r];
  if (l15 == 0) {
#pragma unroll
    for (int r = 0; r < 4; ++r) po[1024 + quad * 4 + r] = lr[r];
  }
}

// ---------------------------------------------------------------------------
// freduce: grid (128, 8), block 256. Block (qt, b): sum nc = (qt>>4)+1 chunk
// partials (deterministic order) and normalize by l. Thread t owns float4 at
// element 4t: row = t>>4, cols (4t)&63.  (unchanged from R7)
// ---------------------------------------------------------------------------
__global__ __launch_bounds__(256)
void freduce(const float* __restrict__ fpart, float* __restrict__ out) {
  const int qt  = blockIdx.x;
  const int b   = blockIdx.y;
  const int tid = threadIdx.x;
  const int nc  = (qt >> 4) + 1;  // ceil(((qt>>2)+1)/4)
  const float* __restrict__ pb = fpart + (size_t)(b * 128 + qt) * 8 * 1040;
  __shared__ float ls[16];
  if (tid < 16) {
    float s = 0.f;
#pragma unroll 1
    for (int i = 0; i < nc; ++i) s += pb[(size_t)i * 1040 + 1024 + tid];
    ls[tid] = s;
  }
  __syncthreads();
  f32x4 a = {0.f, 0.f, 0.f, 0.f};
#pragma unroll 1
  for (int i = 0; i < nc; ++i)
    a += *(const f32x4*)(pb + (size_t)i * 1040 + tid * 4);
  const float inv = 1.0f / ls[tid >> 4];
  a[0] *= inv; a[1] *= inv; a[2] *= inv; a[3] *= inv;
  *(f32x4*)(out + (size_t)(b * T_ + qt * 16 + (tid >> 4)) * H_ + ((tid * 4) & 63)) = a;
}

extern "C" void kernel_launch(void* const* d_in, const int* in_sizes, int n_in,
                              void* d_out, int out_size, void* d_ws, size_t ws_size,
                              hipStream_t stream) {
  const float* x  = (const float*)d_in[0];
  const float* Wk = (const float*)d_in[1];
  const float* Wq = (const float*)d_in[2];
  const float* Wv = (const float*)d_in[3];
  u16*   ws  = (u16*)d_ws;
  u16*   Wct = ws + (size_t)3 * BTH;
  float* fpart = (float*)(ws + (size_t)3 * BTH + 192 * 1024);  // 16B-aligned
  float* out = (float*)d_out;
  wpack<<<dim3(3, 16), 256, 0, stream>>>(Wk, Wq, Wv, Wct);
  qkv_gemm<<<dim3(256), 512, 0, stream>>>(x, Wct, ws);
  flash<<<dim3(144, B_), 256, 0, stream>>>(ws, fpart);
  freduce<<<dim3(128, B_), 256, 0, stream>>>(fpart, out);
}